// Round 5
// baseline (722.576 us; speedup 1.0000x reference)
//
#include <hip/hip_runtime.h>

constexpr int L      = 128;
constexpr int TDIM   = 1024;
constexpr int NBATCH = 128;
constexpr int START  = L - 2; // 126
constexpr int STOP   = L - 1; // 127
constexpr int BSUB   = 16;    // batches per wave
constexpr int NWAVE  = NBATCH / BSUB; // 8 waves, one block

typedef short bf16x8 __attribute__((ext_vector_type(8)));
typedef float f32x4  __attribute__((ext_vector_type(4)));
typedef int   i32x4  __attribute__((ext_vector_type(4)));

union B4 { i32x4 i; bf16x8 v; };

__device__ __forceinline__ short f2bf(float f) {
    unsigned x = __float_as_uint(f);
    return (short)((x + 0x7fffu + ((x >> 16) & 1u)) >> 16); // RNE
}
__device__ __forceinline__ unsigned pkbf(float lo, float hi) {
    unsigned r;
    asm("v_cvt_pk_bf16_f32 %0, %1, %2" : "=v"(r) : "v"(lo), "v"(hi));
    return r;
}

// ---------------------------------------------------------------------------
// Precompute: pexp = masked bf16 exp(pred), chain-lane-sequential layout.
// byte addr = ((blk*1024 + row)*4 + w)*1024 + lane*16   (verified R3/R4)
// ---------------------------------------------------------------------------
__global__ __launch_bounds__(256)
void crf_pexp(const float* __restrict__ pred, const int* __restrict__ seq_len,
              unsigned short* __restrict__ pexp)
{
    int gid  = blockIdx.x * 256 + threadIdx.x;  // 2,097,152 total
    int lane = gid & 63;
    int c    = (gid >> 6) & 3;
    int row  = (gid >> 8) & 1023;
    int blk  = gid >> 18;
    int l15 = lane & 15, l4 = lane >> 4;
    int b = blk * 16 + l15;
    bool live = row < seq_len[b];

    const float* src = pred + ((size_t)b * TDIM + row) * L + 32 * c + 4 * l4;
    f32x4 v0 = *(const f32x4*)(src);        // T = 2c
    f32x4 v1 = *(const f32x4*)(src + 16);   // T = 2c+1

    float e0[4], e1[4];
#pragma unroll
    for (int r = 0; r < 4; ++r) {
        int s0 = 32 * c + 4 * l4 + r;
        int s1 = s0 + 16;
        e0[r] = (live && s0 < 126) ? __expf(v0[r]) : 0.0f;
        e1[r] = (live && s1 < 126) ? __expf(v1[r]) : 0.0f;
    }
    i32x4 out;
    out[0] = (int)pkbf(e0[0], e0[1]);
    out[1] = (int)pkbf(e0[2], e0[3]);
    out[2] = (int)pkbf(e1[0], e1[1]);
    out[3] = (int)pkbf(e1[2], e1[3]);
    *(i32x4*)((char*)pexp + (size_t)gid * 16) = out;
}

// ---------------------------------------------------------------------------
// Chain: ONE block, 8 waves (2 per SIMD). Wave w owns batches [16w,16w+16).
// Register-only recurrence (verified mapping from R3/R4), with:
//  - deferred renorm, trigger checked every 2nd step
//  - register extraction (single store at end)
//  - acc seeded via zero-quad C operand (no per-step acc zeroing)
// ---------------------------------------------------------------------------
struct PB { i32x4 c[4]; };   // one step's pexp chunk (4 x dwordx4 per lane)
struct PF { f32x4 q[8]; };   // fallback: raw pred row

template<bool PEXP>
__global__ __launch_bounds__(512, 1)
void crf_chain(const float* __restrict__ pred,
               const float* __restrict__ trans,
               const int* __restrict__ seq_len,
               const unsigned short* __restrict__ pexp,
               float* __restrict__ fwd_out)
{
    const int tid  = threadIdx.x;
    const int lane = tid & 63;
    const int wave = tid >> 6;          // 0..7
    const int l15 = lane & 15, l4 = lane >> 4;
    const int b   = wave * BSUB + l15;

    // A-frags: A[T][kt] elem e = exp(trans[s][16T + l15]),
    //          s = 16*kt + 64*(e>>2) + 4*l4 + (e&3)      (verified exact)
    bf16x8 A[8][4];
#pragma unroll
    for (int T = 0; T < 8; ++T)
#pragma unroll
        for (int kt = 0; kt < 4; ++kt) {
            bf16x8 v;
#pragma unroll
            for (int e = 0; e < 8; ++e) {
                int s = 16 * kt + 64 * (e >> 2) + 4 * l4 + (e & 3);
                v[e] = f2bf(__expf(trans[s * L + 16 * T + l15]));
            }
            A[T][kt] = v;
        }

    const int srow1 = seq_len[b] + 1;

    int mx = srow1;
#pragma unroll
    for (int d = 1; d < 16; d <<= 1) mx = max(mx, __shfl_xor(mx, d));
    const int tmaxR = __builtin_amdgcn_readfirstlane((mx + 1) & ~1); // even

    B4 B[4];
#pragma unroll
    for (int kt = 0; kt < 4; ++kt) B[kt].i = (i32x4){0, 0, 0, 0};
    if (l4 == 3) B[3].i[3] = 0x3F80;    // START = 1.0

    const f32x4 Z4 = {0.f, 0.f, 0.f, 0.f};   // persistent zero C-operand

    float C = 0.0f;
    bool  applyScale = false;
    float res = 1.0f, resC = 0.0f;

    const char*  pxb = (const char*)pexp + (size_t)wave * 1024 * 4096;
    const float* pfb = pred + (size_t)b * TDIM * L + 4 * l4;

    auto loadPB = [&](PB& p, int row) {
        const i32x4* s = (const i32x4*)(pxb + (size_t)row * 4096) + lane;
        p.c[0] = s[0]; p.c[1] = s[64]; p.c[2] = s[128]; p.c[3] = s[192];
    };
    auto loadPF = [&](PF& p, int row) {
        const f32x4* s = (const f32x4*)(pfb + (size_t)row * L);
#pragma unroll
        for (int T = 0; T < 8; ++T) p.q[T] = s[T * 4];
    };

    auto stepP = [&](int t, PB& pb, bool chk) {
        f32x4 acc[8];
#pragma unroll
        for (int T = 0; T < 8; ++T)
            acc[T] = __builtin_amdgcn_mfma_f32_16x16x32_bf16(A[T][0], B[0].v, Z4, 0, 0, 0);
#pragma unroll
        for (int kt = 1; kt < 4; ++kt)
#pragma unroll
            for (int T = 0; T < 8; ++T)
                acc[T] = __builtin_amdgcn_mfma_f32_16x16x32_bf16(A[T][kt], B[kt].v, acc[T], 0, 0, 0);

        // extraction (STOP = T7,r3 on l4==3 lanes), before P, before C bump
        bool hit = (t == srow1);
        res  = hit ? acc[7][3] : res;
        resC = hit ? C : resC;

        // u = D' * P   (lo = exact shl; hi = raw word, mantissa noise <2^-8)
        float u[8][4];
#pragma unroll
        for (int T = 0; T < 8; ++T) {
            int cI = T >> 1, h = (T & 1) * 2;
            unsigned w0 = (unsigned)pb.c[cI][h + 0];
            unsigned w1 = (unsigned)pb.c[cI][h + 1];
            u[T][0] = acc[T][0] * __uint_as_float(w0 << 16);
            u[T][1] = acc[T][1] * __uint_as_float(w0 & 0xffff0000u);
            u[T][2] = acc[T][2] * __uint_as_float(w1 << 16);
            u[T][3] = acc[T][3] * __uint_as_float(w1 & 0xffff0000u);
        }
        if (applyScale) {
#pragma unroll
            for (int T = 0; T < 8; ++T)
#pragma unroll
                for (int r = 0; r < 4; ++r) u[T][r] *= 0x1p-64f;
            C += 44.3614195558365f;
        }
        applyScale = false;
        if (chk) {
            float m[8];
#pragma unroll
            for (int T = 0; T < 8; ++T)
                m[T] = fmaxf(fmaxf(u[T][0], u[T][1]), fmaxf(u[T][2], u[T][3]));
            float mx4 = fmaxf(fmaxf(fmaxf(m[0], m[1]), fmaxf(m[2], m[3])),
                              fmaxf(fmaxf(m[4], m[5]), fmaxf(m[6], m[7])));
            applyScale = (__ballot(mx4 > 0x1p80f) != 0ull);
        }

#pragma unroll
        for (int kt = 0; kt < 4; ++kt) {
            B[kt].i[0] = (int)pkbf(u[kt][0], u[kt][1]);
            B[kt].i[1] = (int)pkbf(u[kt][2], u[kt][3]);
            B[kt].i[2] = (int)pkbf(u[kt + 4][0], u[kt + 4][1]);
            B[kt].i[3] = (int)pkbf(u[kt + 4][2], u[kt + 4][3]);
        }
        loadPB(pb, min(t + 1, TDIM - 1));
    };

    auto stepF = [&](int t, PF& pf, bool chk) {
        f32x4 acc[8];
#pragma unroll
        for (int T = 0; T < 8; ++T)
            acc[T] = __builtin_amdgcn_mfma_f32_16x16x32_bf16(A[T][0], B[0].v, Z4, 0, 0, 0);
#pragma unroll
        for (int kt = 1; kt < 4; ++kt)
#pragma unroll
            for (int T = 0; T < 8; ++T)
                acc[T] = __builtin_amdgcn_mfma_f32_16x16x32_bf16(A[T][kt], B[kt].v, acc[T], 0, 0, 0);

        bool hit = (t == srow1);
        res  = hit ? acc[7][3] : res;
        resC = hit ? C : resC;

        const bool live = (t < srow1);
        float u[8][4];
#pragma unroll
        for (int T = 0; T < 8; ++T)
#pragma unroll
            for (int r = 0; r < 4; ++r) {
                bool dead = !live || (T == 7 && l4 == 3 && r >= 2);
                u[T][r] = dead ? 0.0f : acc[T][r] * __expf(pf.q[T][r]);
            }
        if (applyScale) {
#pragma unroll
            for (int T = 0; T < 8; ++T)
#pragma unroll
                for (int r = 0; r < 4; ++r) u[T][r] *= 0x1p-64f;
            C += 44.3614195558365f;
        }
        applyScale = false;
        if (chk) {
            float m[8];
#pragma unroll
            for (int T = 0; T < 8; ++T)
                m[T] = fmaxf(fmaxf(u[T][0], u[T][1]), fmaxf(u[T][2], u[T][3]));
            float mx4 = fmaxf(fmaxf(fmaxf(m[0], m[1]), fmaxf(m[2], m[3])),
                              fmaxf(fmaxf(m[4], m[5]), fmaxf(m[6], m[7])));
            applyScale = (__ballot(mx4 > 0x1p80f) != 0ull);
        }
#pragma unroll
        for (int kt = 0; kt < 4; ++kt) {
            B[kt].i[0] = (int)pkbf(u[kt][0], u[kt][1]);
            B[kt].i[1] = (int)pkbf(u[kt][2], u[kt][3]);
            B[kt].i[2] = (int)pkbf(u[kt + 4][0], u[kt + 4][1]);
            B[kt].i[3] = (int)pkbf(u[kt + 4][2], u[kt + 4][3]);
        }
        loadPF(pf, min(t + 1, TDIM - 1));
    };

    if constexpr (PEXP) {
        PB pa, pb_;
        loadPB(pa, 0); loadPB(pb_, 1);
        for (int t0 = 0; t0 < tmaxR; t0 += 2) {
            stepP(t0 + 1, pa, true);    // check step
            stepP(t0 + 2, pb_, false);  // apply step
        }
    } else {
        PF fa, fb;
        loadPF(fa, 0); loadPF(fb, 1);
        for (int t0 = 0; t0 < tmaxR; t0 += 2) {
            stepF(t0 + 1, fa, true);
            stepF(t0 + 2, fb, false);
        }
    }

    if (l4 == 3)
        fwd_out[b] = __logf(res) + resC;
}

// ---------------------------------------------------------------------------
// Gold path score (unchanged, verified exact).
// ---------------------------------------------------------------------------
__global__ __launch_bounds__(256)
void crf_score(const float* __restrict__ pred,
               const float* __restrict__ trans,
               const int* __restrict__ tags,
               const int* __restrict__ seq_len,
               float* __restrict__ score_out)
{
    const int b = blockIdx.x;
    const int tid = threadIdx.x;
    const int sl = seq_len[b];
    const int* tg = tags + b * TDIM;

    float s = 0.0f;
    for (int t = tid; t < sl; t += 256) {
        int tag = tg[t];
        s += pred[((long)b * TDIM + t) * L + tag];
        int prev = (t == 0) ? START : tg[t - 1];
        s += trans[prev * L + tag];
    }
    if (tid == 0) s += trans[tg[sl - 1] * L + STOP];

    __shared__ float red[4];
#pragma unroll
    for (int d = 1; d < 64; d <<= 1) s += __shfl_xor(s, d);
    if ((tid & 63) == 0) red[tid >> 6] = s;
    __syncthreads();
    if (tid == 0) score_out[b] = (red[0] + red[1]) + (red[2] + red[3]);
}

__global__ __launch_bounds__(128)
void crf_combine(const float* __restrict__ fwd,
                 const float* __restrict__ real,
                 float* __restrict__ out)
{
    const int tid = threadIdx.x;
    float s = fwd[tid] - real[tid];
#pragma unroll
    for (int d = 1; d < 64; d <<= 1) s += __shfl_xor(s, d);
    __shared__ float red[2];
    if ((tid & 63) == 0) red[tid >> 6] = s;
    __syncthreads();
    if (tid == 0) out[0] = red[0] + red[1];
}

extern "C" void kernel_launch(void* const* d_in, const int* in_sizes, int n_in,
                              void* d_out, int out_size, void* d_ws, size_t ws_size,
                              hipStream_t stream)
{
    const float* pred    = (const float*)d_in[0];
    const float* trans   = (const float*)d_in[1];
    const int*   tags    = (const int*)d_in[2];
    const int*   seq_len = (const int*)d_in[3];

    float* ws   = (float*)d_ws;
    float* fwd  = ws;        // 128 floats
    float* real = ws + 128;  // 128 floats

    const size_t pexp_bytes = (size_t)NWAVE * 1024 * 4096; // 33.5 MB
    if (ws_size >= 1024 + pexp_bytes) {
        unsigned short* pexp = (unsigned short*)((char*)d_ws + 1024);
        crf_pexp<<<8192, 256, 0, stream>>>(pred, seq_len, pexp);
        crf_chain<true><<<1, 512, 0, stream>>>(pred, trans, seq_len, pexp, fwd);
    } else {
        crf_chain<false><<<1, 512, 0, stream>>>(pred, trans, seq_len, nullptr, fwd);
    }
    crf_score  <<<NBATCH, 256, 0, stream>>>(pred, trans, tags, seq_len, real);
    crf_combine<<<1, 128, 0, stream>>>(fwd, real, (float*)d_out);
}

// Round 6
// 481.341 us; speedup vs baseline: 1.5012x; 1.5012x over previous
//
#include <hip/hip_runtime.h>

constexpr int L      = 128;
constexpr int TDIM   = 1024;
constexpr int NBATCH = 128;
constexpr int START  = L - 2; // 126
constexpr int STOP   = L - 1; // 127
constexpr int BSUB   = 16;    // batches per wave (one wave per block)
constexpr int NBLK   = NBATCH / BSUB; // 8

typedef short bf16x8 __attribute__((ext_vector_type(8)));
typedef float f32x4  __attribute__((ext_vector_type(4)));
typedef int   i32x4  __attribute__((ext_vector_type(4)));

union B4 { i32x4 i; bf16x8 v; };

__device__ __forceinline__ short f2bf(float f) {
    unsigned x = __float_as_uint(f);
    return (short)((x + 0x7fffu + ((x >> 16) & 1u)) >> 16); // RNE
}
__device__ __forceinline__ unsigned pkbf(float lo, float hi) {
    unsigned r;
    asm("v_cvt_pk_bf16_f32 %0, %1, %2" : "=v"(r) : "v"(lo), "v"(hi));
    return r;
}

// ---------------------------------------------------------------------------
// Precompute: pexp = masked bf16 exp(pred), chain-lane-sequential layout.
// byte addr = ((blk*1024 + row)*4 + c)*1024 + lane*16   (verified R4/R5 exact)
// ---------------------------------------------------------------------------
__global__ __launch_bounds__(256)
void crf_pexp(const float* __restrict__ pred, const int* __restrict__ seq_len,
              unsigned short* __restrict__ pexp)
{
    int gid  = blockIdx.x * 256 + threadIdx.x;  // 2,097,152 total
    int lane = gid & 63;
    int c    = (gid >> 6) & 3;
    int row  = (gid >> 8) & 1023;
    int blk  = gid >> 18;
    int l15 = lane & 15, l4 = lane >> 4;
    int b = blk * 16 + l15;
    bool live = row < seq_len[b];

    const float* src = pred + ((size_t)b * TDIM + row) * L + 32 * c + 4 * l4;
    f32x4 v0 = *(const f32x4*)(src);        // T = 2c
    f32x4 v1 = *(const f32x4*)(src + 16);   // T = 2c+1

    float e0[4], e1[4];
#pragma unroll
    for (int r = 0; r < 4; ++r) {
        int s0 = 32 * c + 4 * l4 + r;
        int s1 = s0 + 16;
        e0[r] = (live && s0 < 126) ? __expf(v0[r]) : 0.0f;
        e1[r] = (live && s1 < 126) ? __expf(v1[r]) : 0.0f;
    }
    i32x4 out;
    out[0] = (int)pkbf(e0[0], e0[1]);
    out[1] = (int)pkbf(e0[2], e0[3]);
    out[2] = (int)pkbf(e1[0], e1[1]);
    out[3] = (int)pkbf(e1[2], e1[3]);
    *(i32x4*)((char*)pexp + (size_t)gid * 16) = out;
}

// ---------------------------------------------------------------------------
// Chain: 8 blocks x 1 wave (one chain per SIMD/CU — R4-proven config).
// Register-only recurrence (mapping verified exact), plus:
//  - sched_group_barrier pins MFMA order to 4 groups of 8 independent MFMAs
//    (kt-outer, T-inner) so dependent MFMAs are ~40 cyc apart (no pipe stall)
//  - deferred renorm, trigger checked every 2nd step
//  - register extraction (single store at end)
//  - acc seeded via zero-quad C operand
// ---------------------------------------------------------------------------
struct PB { i32x4 c[4]; };   // one step's pexp chunk (4 x dwordx4 per lane)
struct PF { f32x4 q[8]; };   // fallback: raw pred row

__device__ __forceinline__ void pin_mfma_groups() {
    // 4 ordered clusters of 8 MFMAs (mask 0x8 = MFMA), syncid 0
    __builtin_amdgcn_sched_group_barrier(0x008, 8, 0);
    __builtin_amdgcn_sched_group_barrier(0x008, 8, 0);
    __builtin_amdgcn_sched_group_barrier(0x008, 8, 0);
    __builtin_amdgcn_sched_group_barrier(0x008, 8, 0);
}

template<bool PEXP>
__global__ __launch_bounds__(64, 1)
void crf_chain(const float* __restrict__ pred,
               const float* __restrict__ trans,
               const int* __restrict__ seq_len,
               const unsigned short* __restrict__ pexp,
               float* __restrict__ fwd_out)
{
    const int lane = threadIdx.x;
    const int l15 = lane & 15, l4 = lane >> 4;
    const int blk = blockIdx.x;
    const int b   = blk * BSUB + l15;

    // A-frags: A[T][kt] elem e = exp(trans[s][16T + l15]),
    //          s = 16*kt + 64*(e>>2) + 4*l4 + (e&3)      (verified exact)
    bf16x8 A[8][4];
#pragma unroll
    for (int T = 0; T < 8; ++T)
#pragma unroll
        for (int kt = 0; kt < 4; ++kt) {
            bf16x8 v;
#pragma unroll
            for (int e = 0; e < 8; ++e) {
                int s = 16 * kt + 64 * (e >> 2) + 4 * l4 + (e & 3);
                v[e] = f2bf(__expf(trans[s * L + 16 * T + l15]));
            }
            A[T][kt] = v;
        }

    const int srow1 = seq_len[b] + 1;

    int mx = srow1;
#pragma unroll
    for (int d = 1; d < 16; d <<= 1) mx = max(mx, __shfl_xor(mx, d));
    const int tmaxR = __builtin_amdgcn_readfirstlane((mx + 1) & ~1); // even

    B4 B[4];
#pragma unroll
    for (int kt = 0; kt < 4; ++kt) B[kt].i = (i32x4){0, 0, 0, 0};
    if (l4 == 3) B[3].i[3] = 0x3F80;    // START = 1.0 (elem6 low half)

    const f32x4 Z4 = {0.f, 0.f, 0.f, 0.f};   // persistent zero C-operand

    float C = 0.0f;
    bool  applyScale = false;
    float res = 1.0f, resC = 0.0f;

    const char*  pxb = (const char*)pexp + (size_t)blk * 1024 * 4096;
    const float* pfb = pred + (size_t)b * TDIM * L + 4 * l4;

    auto loadPB = [&](PB& p, int row) {
        const i32x4* s = (const i32x4*)(pxb + (size_t)row * 4096) + lane;
        p.c[0] = s[0]; p.c[1] = s[64]; p.c[2] = s[128]; p.c[3] = s[192];
    };
    auto loadPF = [&](PF& p, int row) {
        const f32x4* s = (const f32x4*)(pfb + (size_t)row * L);
#pragma unroll
        for (int T = 0; T < 8; ++T) p.q[T] = s[T * 4];
    };

    auto stepP = [&](int t, PB& pb, bool chk) {
        f32x4 acc[8];
#pragma unroll
        for (int T = 0; T < 8; ++T)
            acc[T] = __builtin_amdgcn_mfma_f32_16x16x32_bf16(A[T][0], B[0].v, Z4, 0, 0, 0);
#pragma unroll
        for (int kt = 1; kt < 4; ++kt)
#pragma unroll
            for (int T = 0; T < 8; ++T)
                acc[T] = __builtin_amdgcn_mfma_f32_16x16x32_bf16(A[T][kt], B[kt].v, acc[T], 0, 0, 0);
        pin_mfma_groups();

        // extraction (STOP = T7,r3 on l4==3 lanes), before P, before C bump
        bool hit = (t == srow1);
        res  = hit ? acc[7][3] : res;
        resC = hit ? C : resC;

        // u = D' * P   (lo = exact shl; hi = raw word, mantissa noise <2^-8)
        float u[8][4];
#pragma unroll
        for (int T = 0; T < 8; ++T) {
            int cI = T >> 1, h = (T & 1) * 2;
            unsigned w0 = (unsigned)pb.c[cI][h + 0];
            unsigned w1 = (unsigned)pb.c[cI][h + 1];
            u[T][0] = acc[T][0] * __uint_as_float(w0 << 16);
            u[T][1] = acc[T][1] * __uint_as_float(w0 & 0xffff0000u);
            u[T][2] = acc[T][2] * __uint_as_float(w1 << 16);
            u[T][3] = acc[T][3] * __uint_as_float(w1 & 0xffff0000u);
        }
        if (applyScale) {
#pragma unroll
            for (int T = 0; T < 8; ++T)
#pragma unroll
                for (int r = 0; r < 4; ++r) u[T][r] *= 0x1p-64f;
            C += 44.3614195558365f;
        }
        applyScale = false;
        if (chk) {
            float m[8];
#pragma unroll
            for (int T = 0; T < 8; ++T)
                m[T] = fmaxf(fmaxf(u[T][0], u[T][1]), fmaxf(u[T][2], u[T][3]));
            float mx4 = fmaxf(fmaxf(fmaxf(m[0], m[1]), fmaxf(m[2], m[3])),
                              fmaxf(fmaxf(m[4], m[5]), fmaxf(m[6], m[7])));
            applyScale = (__ballot(mx4 > 0x1p80f) != 0ull);
        }

#pragma unroll
        for (int kt = 0; kt < 4; ++kt) {
            B[kt].i[0] = (int)pkbf(u[kt][0], u[kt][1]);
            B[kt].i[1] = (int)pkbf(u[kt][2], u[kt][3]);
            B[kt].i[2] = (int)pkbf(u[kt + 4][0], u[kt + 4][1]);
            B[kt].i[3] = (int)pkbf(u[kt + 4][2], u[kt + 4][3]);
        }
        loadPB(pb, min(t + 1, TDIM - 1));
    };

    auto stepF = [&](int t, PF& pf, bool chk) {
        f32x4 acc[8];
#pragma unroll
        for (int T = 0; T < 8; ++T)
            acc[T] = __builtin_amdgcn_mfma_f32_16x16x32_bf16(A[T][0], B[0].v, Z4, 0, 0, 0);
#pragma unroll
        for (int kt = 1; kt < 4; ++kt)
#pragma unroll
            for (int T = 0; T < 8; ++T)
                acc[T] = __builtin_amdgcn_mfma_f32_16x16x32_bf16(A[T][kt], B[kt].v, acc[T], 0, 0, 0);
        pin_mfma_groups();

        bool hit = (t == srow1);
        res  = hit ? acc[7][3] : res;
        resC = hit ? C : resC;

        const bool live = (t < srow1);
        float u[8][4];
#pragma unroll
        for (int T = 0; T < 8; ++T)
#pragma unroll
            for (int r = 0; r < 4; ++r) {
                bool dead = !live || (T == 7 && l4 == 3 && r >= 2);
                u[T][r] = dead ? 0.0f : acc[T][r] * __expf(pf.q[T][r]);
            }
        if (applyScale) {
#pragma unroll
            for (int T = 0; T < 8; ++T)
#pragma unroll
                for (int r = 0; r < 4; ++r) u[T][r] *= 0x1p-64f;
            C += 44.3614195558365f;
        }
        applyScale = false;
        if (chk) {
            float m[8];
#pragma unroll
            for (int T = 0; T < 8; ++T)
                m[T] = fmaxf(fmaxf(u[T][0], u[T][1]), fmaxf(u[T][2], u[T][3]));
            float mx4 = fmaxf(fmaxf(fmaxf(m[0], m[1]), fmaxf(m[2], m[3])),
                              fmaxf(fmaxf(m[4], m[5]), fmaxf(m[6], m[7])));
            applyScale = (__ballot(mx4 > 0x1p80f) != 0ull);
        }
#pragma unroll
        for (int kt = 0; kt < 4; ++kt) {
            B[kt].i[0] = (int)pkbf(u[kt][0], u[kt][1]);
            B[kt].i[1] = (int)pkbf(u[kt][2], u[kt][3]);
            B[kt].i[2] = (int)pkbf(u[kt + 4][0], u[kt + 4][1]);
            B[kt].i[3] = (int)pkbf(u[kt + 4][2], u[kt + 4][3]);
        }
        loadPF(pf, min(t + 1, TDIM - 1));
    };

    if constexpr (PEXP) {
        PB pa, pb_;
        loadPB(pa, 0); loadPB(pb_, 1);
        for (int t0 = 0; t0 < tmaxR; t0 += 2) {
            stepP(t0 + 1, pa, true);    // check step
            stepP(t0 + 2, pb_, false);  // apply step
        }
    } else {
        PF fa, fb;
        loadPF(fa, 0); loadPF(fb, 1);
        for (int t0 = 0; t0 < tmaxR; t0 += 2) {
            stepF(t0 + 1, fa, true);
            stepF(t0 + 2, fb, false);
        }
    }

    if (l4 == 3)
        fwd_out[b] = __logf(res) + resC;
}

// ---------------------------------------------------------------------------
// Gold path score (unchanged, verified exact).
// ---------------------------------------------------------------------------
__global__ __launch_bounds__(256)
void crf_score(const float* __restrict__ pred,
               const float* __restrict__ trans,
               const int* __restrict__ tags,
               const int* __restrict__ seq_len,
               float* __restrict__ score_out)
{
    const int b = blockIdx.x;
    const int tid = threadIdx.x;
    const int sl = seq_len[b];
    const int* tg = tags + b * TDIM;

    float s = 0.0f;
    for (int t = tid; t < sl; t += 256) {
        int tag = tg[t];
        s += pred[((long)b * TDIM + t) * L + tag];
        int prev = (t == 0) ? START : tg[t - 1];
        s += trans[prev * L + tag];
    }
    if (tid == 0) s += trans[tg[sl - 1] * L + STOP];

    __shared__ float red[4];
#pragma unroll
    for (int d = 1; d < 64; d <<= 1) s += __shfl_xor(s, d);
    if ((tid & 63) == 0) red[tid >> 6] = s;
    __syncthreads();
    if (tid == 0) score_out[b] = (red[0] + red[1]) + (red[2] + red[3]);
}

__global__ __launch_bounds__(128)
void crf_combine(const float* __restrict__ fwd,
                 const float* __restrict__ real,
                 float* __restrict__ out)
{
    const int tid = threadIdx.x;
    float s = fwd[tid] - real[tid];
#pragma unroll
    for (int d = 1; d < 64; d <<= 1) s += __shfl_xor(s, d);
    __shared__ float red[2];
    if ((tid & 63) == 0) red[tid >> 6] = s;
    __syncthreads();
    if (tid == 0) out[0] = red[0] + red[1];
}

extern "C" void kernel_launch(void* const* d_in, const int* in_sizes, int n_in,
                              void* d_out, int out_size, void* d_ws, size_t ws_size,
                              hipStream_t stream)
{
    const float* pred    = (const float*)d_in[0];
    const float* trans   = (const float*)d_in[1];
    const int*   tags    = (const int*)d_in[2];
    const int*   seq_len = (const int*)d_in[3];

    float* ws   = (float*)d_ws;
    float* fwd  = ws;        // 128 floats
    float* real = ws + 128;  // 128 floats

    const size_t pexp_bytes = (size_t)NBLK * 1024 * 4096; // 33.5 MB
    if (ws_size >= 1024 + pexp_bytes) {
        unsigned short* pexp = (unsigned short*)((char*)d_ws + 1024);
        crf_pexp<<<8192, 256, 0, stream>>>(pred, seq_len, pexp);
        crf_chain<true><<<NBLK, 64, 0, stream>>>(pred, trans, seq_len, pexp, fwd);
    } else {
        crf_chain<false><<<NBLK, 64, 0, stream>>>(pred, trans, seq_len, nullptr, fwd);
    }
    crf_score  <<<NBATCH, 256, 0, stream>>>(pred, trans, tags, seq_len, real);
    crf_combine<<<1, 128, 0, stream>>>(fwd, real, (float*)d_out);
}

// Round 8
// 480.719 us; speedup vs baseline: 1.5031x; 1.0013x over previous
//
#include <hip/hip_runtime.h>

constexpr int L      = 128;
constexpr int TDIM   = 1024;
constexpr int NBATCH = 128;
constexpr int START  = L - 2; // 126
constexpr int STOP   = L - 1; // 127
constexpr int BSUB   = 16;    // batches per wave (one wave per block)
constexpr int NBLK   = NBATCH / BSUB; // 8

typedef short bf16x8 __attribute__((ext_vector_type(8)));
typedef float f32x4  __attribute__((ext_vector_type(4)));
typedef int   i32x4  __attribute__((ext_vector_type(4)));

union B4 { i32x4 i; bf16x8 v; };

__device__ __forceinline__ short f2bf(float f) {
    unsigned x = __float_as_uint(f);
    return (short)((x + 0x7fffu + ((x >> 16) & 1u)) >> 16); // RNE
}
__device__ __forceinline__ unsigned pkbf(float lo, float hi) {
    unsigned r;
    asm("v_cvt_pk_bf16_f32 %0, %1, %2" : "=v"(r) : "v"(lo), "v"(hi));
    return r;
}

// ---------------------------------------------------------------------------
// Precompute: pexp = masked bf16 exp(pred), chain-lane-sequential layout.
// byte addr = ((blk*1024 + row)*4 + c)*1024 + lane*16   (verified exact)
// ---------------------------------------------------------------------------
__global__ __launch_bounds__(256)
void crf_pexp(const float* __restrict__ pred, const int* __restrict__ seq_len,
              unsigned short* __restrict__ pexp)
{
    int gid  = blockIdx.x * 256 + threadIdx.x;  // 2,097,152 total
    int lane = gid & 63;
    int c    = (gid >> 6) & 3;
    int row  = (gid >> 8) & 1023;
    int blk  = gid >> 18;
    int l15 = lane & 15, l4 = lane >> 4;
    int b = blk * 16 + l15;
    bool live = row < seq_len[b];

    const float* src = pred + ((size_t)b * TDIM + row) * L + 32 * c + 4 * l4;
    f32x4 v0 = *(const f32x4*)(src);        // T = 2c
    f32x4 v1 = *(const f32x4*)(src + 16);   // T = 2c+1

    float e0[4], e1[4];
#pragma unroll
    for (int r = 0; r < 4; ++r) {
        int s0 = 32 * c + 4 * l4 + r;
        int s1 = s0 + 16;
        e0[r] = (live && s0 < 126) ? __expf(v0[r]) : 0.0f;
        e1[r] = (live && s1 < 126) ? __expf(v1[r]) : 0.0f;
    }
    i32x4 out;
    out[0] = (int)pkbf(e0[0], e0[1]);
    out[1] = (int)pkbf(e0[2], e0[3]);
    out[2] = (int)pkbf(e1[0], e1[1]);
    out[3] = (int)pkbf(e1[2], e1[3]);
    *(i32x4*)((char*)pexp + (size_t)gid * 16) = out;
}

// ---------------------------------------------------------------------------
// Chain: 8 blocks x 1 wave. Software-pipelined at kt granularity:
// stages (unpack step t -> pack B) interleave with MFMA groups (step t+1).
// Order per iteration: [s0][s1][g0][s2][g1][s3][g2][g3].
// ---------------------------------------------------------------------------
struct PB { i32x4 c[4]; };   // one step's pexp chunk (4 x dwordx4 per lane)
struct PF { f32x4 q[8]; };   // fallback: raw pred row

// stage TA (=kt), TB (=kt+4): unpack ACCIN[TA],[TB] * P -> pack B[TA]
#define STAGE(TA, TB, ACCIN, PBUF, CHK, SCL)                                 \
  {                                                                          \
    unsigned wa0 = (unsigned)PBUF.c[(TA) >> 1][((TA) & 1) * 2 + 0];          \
    unsigned wa1 = (unsigned)PBUF.c[(TA) >> 1][((TA) & 1) * 2 + 1];          \
    unsigned wb0 = (unsigned)PBUF.c[(TB) >> 1][((TB) & 1) * 2 + 0];          \
    unsigned wb1 = (unsigned)PBUF.c[(TB) >> 1][((TB) & 1) * 2 + 1];          \
    float ua0 = ACCIN[TA][0] * __uint_as_float(wa0 << 16);                   \
    float ua1 = ACCIN[TA][1] * __uint_as_float(wa0 & 0xffff0000u);           \
    float ua2 = ACCIN[TA][2] * __uint_as_float(wa1 << 16);                   \
    float ua3 = ACCIN[TA][3] * __uint_as_float(wa1 & 0xffff0000u);           \
    float ub0 = ACCIN[TB][0] * __uint_as_float(wb0 << 16);                   \
    float ub1 = ACCIN[TB][1] * __uint_as_float(wb0 & 0xffff0000u);           \
    float ub2 = ACCIN[TB][2] * __uint_as_float(wb1 << 16);                   \
    float ub3 = ACCIN[TB][3] * __uint_as_float(wb1 & 0xffff0000u);           \
    if ((SCL) && applyScale) {                                               \
      ua0 *= 0x1p-64f; ua1 *= 0x1p-64f; ua2 *= 0x1p-64f; ua3 *= 0x1p-64f;    \
      ub0 *= 0x1p-64f; ub1 *= 0x1p-64f; ub2 *= 0x1p-64f; ub3 *= 0x1p-64f;    \
    }                                                                        \
    if (CHK) {                                                               \
      mloc = fmaxf(mloc, fmaxf(fmaxf(fmaxf(ua0, ua1), fmaxf(ua2, ua3)),      \
                               fmaxf(fmaxf(ub0, ub1), fmaxf(ub2, ub3))));    \
    }                                                                        \
    B[TA].i[0] = (int)pkbf(ua0, ua1);                                        \
    B[TA].i[1] = (int)pkbf(ua2, ua3);                                        \
    B[TA].i[2] = (int)pkbf(ub0, ub1);                                        \
    B[TA].i[3] = (int)pkbf(ub2, ub3);                                        \
    __builtin_amdgcn_sched_group_barrier(0x002, 20, 0);                      \
  }

// MFMA group kt: T issue order 0,4,1,5,2,6,3,7 (finalize acc[0],acc[4] first)
#define GROUP(ACCO, KT, SEED)                                                \
  {                                                                          \
    ACCO[0] = __builtin_amdgcn_mfma_f32_16x16x32_bf16(A[0][KT], B[KT].v, (SEED) ? Z4 : ACCO[0], 0, 0, 0); \
    ACCO[4] = __builtin_amdgcn_mfma_f32_16x16x32_bf16(A[4][KT], B[KT].v, (SEED) ? Z4 : ACCO[4], 0, 0, 0); \
    ACCO[1] = __builtin_amdgcn_mfma_f32_16x16x32_bf16(A[1][KT], B[KT].v, (SEED) ? Z4 : ACCO[1], 0, 0, 0); \
    ACCO[5] = __builtin_amdgcn_mfma_f32_16x16x32_bf16(A[5][KT], B[KT].v, (SEED) ? Z4 : ACCO[5], 0, 0, 0); \
    ACCO[2] = __builtin_amdgcn_mfma_f32_16x16x32_bf16(A[2][KT], B[KT].v, (SEED) ? Z4 : ACCO[2], 0, 0, 0); \
    ACCO[6] = __builtin_amdgcn_mfma_f32_16x16x32_bf16(A[6][KT], B[KT].v, (SEED) ? Z4 : ACCO[6], 0, 0, 0); \
    ACCO[3] = __builtin_amdgcn_mfma_f32_16x16x32_bf16(A[3][KT], B[KT].v, (SEED) ? Z4 : ACCO[3], 0, 0, 0); \
    ACCO[7] = __builtin_amdgcn_mfma_f32_16x16x32_bf16(A[7][KT], B[KT].v, (SEED) ? Z4 : ACCO[7], 0, 0, 0); \
    __builtin_amdgcn_sched_group_barrier(0x008, 8, 0);                       \
  }

// One pipelined iteration: unpack step tS (ACCIN) -> B; MFMA step tS+1 (ACCOUT)
#define ITER(T_, ACCIN, ACCOUT, PBUF, CHK, SCL)                              \
  {                                                                          \
    const int tS = (T_);                                                     \
    float mloc = 0.0f; (void)mloc;                                           \
    STAGE(0, 4, ACCIN, PBUF, CHK, SCL)                                       \
    STAGE(1, 5, ACCIN, PBUF, CHK, SCL)                                       \
    GROUP(ACCOUT, 0, true)                                                   \
    STAGE(2, 6, ACCIN, PBUF, CHK, SCL)                                       \
    GROUP(ACCOUT, 1, false)                                                  \
    STAGE(3, 7, ACCIN, PBUF, CHK, SCL)                                       \
    { bool hit = (tS == srow1);                                              \
      res  = hit ? ACCIN[7][3] : res;                                        \
      resC = hit ? C : resC; }                                               \
    if ((SCL) && applyScale) { C += 44.3614195558365f; applyScale = false; } \
    GROUP(ACCOUT, 2, false)                                                  \
    GROUP(ACCOUT, 3, false)                                                  \
    if (CHK) applyScale = (__ballot(mloc > 0x1p80f) != 0ull);                \
    loadPB(PBUF, min(tS + 1, TDIM - 1));                                     \
  }

template<bool PEXP>
__global__ __launch_bounds__(64, 1)
void crf_chain(const float* __restrict__ pred,
               const float* __restrict__ trans,
               const int* __restrict__ seq_len,
               const unsigned short* __restrict__ pexp,
               float* __restrict__ fwd_out)
{
    const int lane = threadIdx.x;
    const int l15 = lane & 15, l4 = lane >> 4;
    const int blk = blockIdx.x;
    const int b   = blk * BSUB + l15;

    // A-frags: A[T][kt] elem e = exp(trans[s][16T + l15]),
    //          s = 16*kt + 64*(e>>2) + 4*l4 + (e&3)      (verified exact)
    bf16x8 A[8][4];
#pragma unroll
    for (int T = 0; T < 8; ++T)
#pragma unroll
        for (int kt = 0; kt < 4; ++kt) {
            bf16x8 v;
#pragma unroll
            for (int e = 0; e < 8; ++e) {
                int s = 16 * kt + 64 * (e >> 2) + 4 * l4 + (e & 3);
                v[e] = f2bf(__expf(trans[s * L + 16 * T + l15]));
            }
            A[T][kt] = v;
        }

    const int srow1 = seq_len[b] + 1;

    int mx = srow1;
#pragma unroll
    for (int d = 1; d < 16; d <<= 1) mx = max(mx, __shfl_xor(mx, d));
    const int tmaxR = __builtin_amdgcn_readfirstlane((mx + 1) & ~1); // even

    B4 B[4];
#pragma unroll
    for (int kt = 0; kt < 4; ++kt) B[kt].i = (i32x4){0, 0, 0, 0};
    if (l4 == 3) B[3].i[3] = 0x3F80;    // START = 1.0 (elem6 low half)

    const f32x4 Z4 = {0.f, 0.f, 0.f, 0.f};   // persistent zero C-operand

    float C = 0.0f;
    bool  applyScale = false;
    float res = 1.0f, resC = 0.0f;

    const char*  pxb = (const char*)pexp + (size_t)blk * 1024 * 4096;
    const float* pfb = pred + (size_t)b * TDIM * L + 4 * l4;

    auto loadPB = [&](PB& p, int row) {
        const i32x4* s = (const i32x4*)(pxb + (size_t)row * 4096) + lane;
        p.c[0] = s[0]; p.c[1] = s[64]; p.c[2] = s[128]; p.c[3] = s[192];
    };
    auto loadPF = [&](PF& p, int row) {
        const f32x4* s = (const f32x4*)(pfb + (size_t)row * L);
#pragma unroll
        for (int T = 0; T < 8; ++T) p.q[T] = s[T * 4];
    };

    if constexpr (PEXP) {
        PB pa, pb_;
        loadPB(pa, 0); loadPB(pb_, 1);

        f32x4 accX[8], accY[8];
        // Prologue: accX = D_1 = A @ B_1 (B_1 = packed u0)
        GROUP(accX, 0, true)
        GROUP(accX, 1, false)
        GROUP(accX, 2, false)
        GROUP(accX, 3, false)

        for (int t0 = 1; t0 < tmaxR; t0 += 2) {
            ITER(t0,     accX, accY, pa,  true,  false)   // check step
            ITER(t0 + 1, accY, accX, pb_, false, true)    // apply step
        }
    } else {
        // Fallback (no workspace): R6-style serialized steps on raw pred.
        PF fa, fb;
        loadPF(fa, 0); loadPF(fb, 1);
        f32x4 acc[8];
        auto stepF = [&](int t, PF& pf, bool chk) {
#pragma unroll
            for (int T = 0; T < 8; ++T)
                acc[T] = __builtin_amdgcn_mfma_f32_16x16x32_bf16(A[T][0], B[0].v, Z4, 0, 0, 0);
#pragma unroll
            for (int kt = 1; kt < 4; ++kt)
#pragma unroll
                for (int T = 0; T < 8; ++T)
                    acc[T] = __builtin_amdgcn_mfma_f32_16x16x32_bf16(A[T][kt], B[kt].v, acc[T], 0, 0, 0);

            bool hit = (t == srow1);
            res  = hit ? acc[7][3] : res;
            resC = hit ? C : resC;

            const bool live = (t < srow1);
            float u[8][4];
#pragma unroll
            for (int T = 0; T < 8; ++T)
#pragma unroll
                for (int r = 0; r < 4; ++r) {
                    bool dead = !live || (T == 7 && l4 == 3 && r >= 2);
                    u[T][r] = dead ? 0.0f : acc[T][r] * __expf(pf.q[T][r]);
                }
            if (applyScale) {
#pragma unroll
                for (int T = 0; T < 8; ++T)
#pragma unroll
                    for (int r = 0; r < 4; ++r) u[T][r] *= 0x1p-64f;
                C += 44.3614195558365f;
            }
            applyScale = false;
            if (chk) {
                float m[8];
#pragma unroll
                for (int T = 0; T < 8; ++T)
                    m[T] = fmaxf(fmaxf(u[T][0], u[T][1]), fmaxf(u[T][2], u[T][3]));
                float mx4 = fmaxf(fmaxf(fmaxf(m[0], m[1]), fmaxf(m[2], m[3])),
                                  fmaxf(fmaxf(m[4], m[5]), fmaxf(m[6], m[7])));
                applyScale = (__ballot(mx4 > 0x1p80f) != 0ull);
            }
#pragma unroll
            for (int kt = 0; kt < 4; ++kt) {
                B[kt].i[0] = (int)pkbf(u[kt][0], u[kt][1]);
                B[kt].i[1] = (int)pkbf(u[kt][2], u[kt][3]);
                B[kt].i[2] = (int)pkbf(u[kt + 4][0], u[kt + 4][1]);
                B[kt].i[3] = (int)pkbf(u[kt + 4][2], u[kt + 4][3]);
            }
            loadPF(pf, min(t + 1, TDIM - 1));
        };
        for (int t0 = 0; t0 < tmaxR; t0 += 2) {
            stepF(t0 + 1, fa, true);
            stepF(t0 + 2, fb, false);
        }
    }

    if (l4 == 3)
        fwd_out[b] = __logf(res) + resC;
}

// ---------------------------------------------------------------------------
// Gold path score (unchanged, verified exact).
// ---------------------------------------------------------------------------
__global__ __launch_bounds__(256)
void crf_score(const float* __restrict__ pred,
               const float* __restrict__ trans,
               const int* __restrict__ tags,
               const int* __restrict__ seq_len,
               float* __restrict__ score_out)
{
    const int b = blockIdx.x;
    const int tid = threadIdx.x;
    const int sl = seq_len[b];
    const int* tg = tags + b * TDIM;

    float s = 0.0f;
    for (int t = tid; t < sl; t += 256) {
        int tag = tg[t];
        s += pred[((long)b * TDIM + t) * L + tag];
        int prev = (t == 0) ? START : tg[t - 1];
        s += trans[prev * L + tag];
    }
    if (tid == 0) s += trans[tg[sl - 1] * L + STOP];

    __shared__ float red[4];
#pragma unroll
    for (int d = 1; d < 64; d <<= 1) s += __shfl_xor(s, d);
    if ((tid & 63) == 0) red[tid >> 6] = s;
    __syncthreads();
    if (tid == 0) score_out[b] = (red[0] + red[1]) + (red[2] + red[3]);
}

__global__ __launch_bounds__(128)
void crf_combine(const float* __restrict__ fwd,
                 const float* __restrict__ real,
                 float* __restrict__ out)
{
    const int tid = threadIdx.x;
    float s = fwd[tid] - real[tid];
#pragma unroll
    for (int d = 1; d < 64; d <<= 1) s += __shfl_xor(s, d);
    __shared__ float red[2];
    if ((tid & 63) == 0) red[tid >> 6] = s;
    __syncthreads();
    if (tid == 0) out[0] = red[0] + red[1];
}

extern "C" void kernel_launch(void* const* d_in, const int* in_sizes, int n_in,
                              void* d_out, int out_size, void* d_ws, size_t ws_size,
                              hipStream_t stream)
{
    const float* pred    = (const float*)d_in[0];
    const float* trans   = (const float*)d_in[1];
    const int*   tags    = (const int*)d_in[2];
    const int*   seq_len = (const int*)d_in[3];

    float* ws   = (float*)d_ws;
    float* fwd  = ws;        // 128 floats
    float* real = ws + 128;  // 128 floats

    const size_t pexp_bytes = (size_t)NBLK * 1024 * 4096; // 33.5 MB
    if (ws_size >= 1024 + pexp_bytes) {
        unsigned short* pexp = (unsigned short*)((char*)d_ws + 1024);
        crf_pexp<<<8192, 256, 0, stream>>>(pred, seq_len, pexp);
        crf_chain<true><<<NBLK, 64, 0, stream>>>(pred, trans, seq_len, pexp, fwd);
    } else {
        crf_chain<false><<<NBLK, 64, 0, stream>>>(pred, trans, seq_len, nullptr, fwd);
    }
    crf_score  <<<NBATCH, 256, 0, stream>>>(pred, trans, tags, seq_len, real);
    crf_combine<<<1, 128, 0, stream>>>(fwd, real, (float*)d_out);
}